// Round 1
// baseline (213.452 us; speedup 1.0000x reference)
//
#include <hip/hip_runtime.h>
#include <math.h>

#define BATCH 8192
#define L 100
#define EMB 16
#define SPB 16   // samples per block (16 lanes per sample)
#define NCH 384  // 4 fields * 6 pools * 16 emb channels

// ---------------- workspace layout ----------------
// pooled : float [4][BATCH][6][16]            = 3,145,728 floats = 12,582,912 B
// sums   : double[384]
// sumsqs : double[384]
// coefA  : float [384]
// coefB  : float [384]
#define POOLED_FLOATS (4 * BATCH * 96)
#define POOLED_BYTES  (POOLED_FLOATS * 4)

__global__ __launch_bounds__(256) void zero_stats_kernel(double* sums) {
    // zero 768 doubles (sums + sumsqs contiguous)
    for (int i = threadIdx.x; i < 768; i += 256) sums[i] = 0.0;
}

__global__ __launch_bounds__(256) void pool_kernel(
    const int* __restrict__ ids_ug, const int* __restrict__ ids_urb,
    const int* __restrict__ ids_mg, const int* __restrict__ ids_mt,
    const int* __restrict__ len_ug, const int* __restrict__ len_urb,
    const int* __restrict__ len_mg, const int* __restrict__ len_mt,
    const float* __restrict__ emb_movie, const float* __restrict__ emb_tag,
    const float* __restrict__ emb_genre,
    const float* __restrict__ att_movie, const float* __restrict__ att_tag,
    const float* __restrict__ att_genre,
    float* __restrict__ pooled, double* __restrict__ sums, double* __restrict__ sumsqs)
{
    const int f = blockIdx.y;
    const int* ids; const int* lens; const float* tab; const float* atab;
    switch (f) {
        case 0: ids = ids_ug;  lens = len_ug;  tab = emb_genre; atab = att_genre; break;
        case 1: ids = ids_urb; lens = len_urb; tab = emb_movie; atab = att_movie; break;
        case 2: ids = ids_mg;  lens = len_mg;  tab = emb_genre; atab = att_genre; break;
        default:ids = ids_mt;  lens = len_mt;  tab = emb_tag;   atab = att_tag;   break;
    }
    const int tid = threadIdx.x;
    const int sub = tid >> 4;       // sample within block
    const int e   = tid & 15;       // embedding dim (lane within 16-group)
    const int b   = blockIdx.x * SPB + sub;
    const int ln  = lens[b];

    float s = 0.f, ssq = 0.f, attacc = 0.f, expsum = 0.f;
    float bestmx = -1e30f, mxv = 0.f;
    float bestmn =  1e30f, mnv = 0.f;

    const int* idrow = ids + (size_t)b * L;
    for (int l = 0; l < L; ++l) {
        int id = idrow[l];
        float maskf = (l < ln) ? 1.f : 0.f;
        float v  = tab[(size_t)id * EMB + e] * maskf;
        float aw = atab[id] * maskf;
        s += v;
        float v2 = v * v;
        ssq += v2;
        // l2 = sum of v^2 over the 16 lanes of this sample
        float l2 = v2;
        l2 += __shfl_xor(l2, 1);
        l2 += __shfl_xor(l2, 2);
        l2 += __shfl_xor(l2, 4);
        l2 += __shfl_xor(l2, 8);
        // first-max semantics (strict >), matches jnp.argmax
        if (l2 > bestmx) { bestmx = l2; mxv = v; }
        // argmin over where(l2==0, 9999, l2), first-min semantics
        float l2m = (l2 == 0.f) ? 9999.f : l2;
        if (l2m < bestmn) { bestmn = l2m; mnv = v; }
        // softmax over L including padded zeros (exp(0)=1 participates)
        float ew = expf(aw);
        expsum += ew;
        attacc += v * ew;
    }

    float mean = s * (1.0f / L);
    float ko = 0.5f * (s * s - ssq);
    float kn2 = ko * ko;
    kn2 += __shfl_xor(kn2, 1);
    kn2 += __shfl_xor(kn2, 2);
    kn2 += __shfl_xor(kn2, 4);
    kn2 += __shfl_xor(kn2, 8);
    float nrm = sqrtf(kn2);
    ko = ko / fmaxf(nrm, 1e-12f);
    float at = attacc / expsum;

    float pv[6] = { s, mean, mxv, mnv, ko, at };

    // write pooled [f][b][p][e]
    float* prow = pooled + ((size_t)(f * BATCH + b)) * 96 + e;
    __shared__ float tile[SPB][96];
    #pragma unroll
    for (int p = 0; p < 6; ++p) {
        prow[p * 16] = pv[p];
        tile[sub][p * 16 + e] = pv[p];
    }
    __syncthreads();
    // block-level partial stats -> double atomics (96 channels for this field)
    if (tid < 96) {
        float sm = 0.f, sq = 0.f;
        #pragma unroll
        for (int s2 = 0; s2 < SPB; ++s2) {
            float x = tile[s2][tid];
            sm += x;
            sq += x * x;
        }
        atomicAdd(&sums[f * 96 + tid],   (double)sm);
        atomicAdd(&sumsqs[f * 96 + tid], (double)sq);
    }
}

__global__ __launch_bounds__(384) void coef_kernel(
    const double* __restrict__ sums, const double* __restrict__ sumsqs,
    const float* __restrict__ gamma, const float* __restrict__ beta,
    const float* __restrict__ alpha,
    float* __restrict__ coefA, float* __restrict__ coefB)
{
    int c = threadIdx.x;          // 0..383  = f*96 + p*16 + e
    if (c >= NCH) return;
    int f = c / 96;
    int p = (c % 96) >> 4;
    double mu  = sums[c]   * (1.0 / BATCH);
    double var = sumsqs[c] * (1.0 / BATCH) - mu * mu;
    float inv = (float)(1.0 / sqrt(var + 1e-5));
    float g  = gamma[c];
    float bb = beta[c];
    // softmax over alpha[f][0..5]
    float amax = -1e30f;
    for (int q = 0; q < 6; ++q) amax = fmaxf(amax, alpha[f * 6 + q]);
    float wsum = 0.f;
    for (int q = 0; q < 6; ++q) wsum += expf(alpha[f * 6 + q] - amax);
    float wp = expf(alpha[f * 6 + p] - amax) / wsum;
    float muf = (float)mu;
    coefA[c] = wp * g * inv;
    coefB[c] = wp * (bb - g * muf * inv);
}

__global__ __launch_bounds__(256) void final_kernel(
    const int* __restrict__ uid, const int* __restrict__ mid, const int* __restrict__ yr,
    const float* __restrict__ emb_user, const float* __restrict__ emb_movie,
    const float* __restrict__ emb_year,
    const float* __restrict__ pooled,
    const float* __restrict__ coefA, const float* __restrict__ coefB,
    const float* __restrict__ W1, const float* __restrict__ b1,
    const float* __restrict__ W2, const float* __restrict__ b2,
    const float* __restrict__ W3, const float* __restrict__ b3,
    float* __restrict__ out)
{
    __shared__ float sW1[112 * 64];
    __shared__ float sW2[64 * 32];
    __shared__ float sW3[32];
    __shared__ float sb1[64];
    __shared__ float sb2[32];
    __shared__ float xt[SPB][112];
    __shared__ float h1t[SPB][64];

    const int tid = threadIdx.x;
    for (int i = tid; i < 112 * 64; i += 256) sW1[i] = W1[i];
    for (int i = tid; i < 64 * 32;  i += 256) sW2[i] = W2[i];
    if (tid < 32) sW3[tid] = W3[tid];
    if (tid < 64) sb1[tid] = b1[tid];
    if (tid < 32) sb2[tid] = b2[tid];

    const int sub = tid >> 4;
    const int e   = tid & 15;
    const int b   = blockIdx.x * SPB + sub;

    // emb1: [user(16) | movie(16) | year(16)]
    xt[sub][e]      = emb_user [(size_t)uid[b] * EMB + e];
    xt[sub][16 + e] = emb_movie[(size_t)mid[b] * EMB + e];
    xt[sub][32 + e] = emb_year [(size_t)yr[b]  * EMB + e];

    // 4 pooled fields: apply folded BN+softmax-weight coefficients
    #pragma unroll
    for (int f = 0; f < 4; ++f) {
        const float* pr = pooled + ((size_t)(f * BATCH + b)) * 96;
        float acc = 0.f;
        #pragma unroll
        for (int p = 0; p < 6; ++p) {
            int c = f * 96 + p * 16 + e;
            acc += coefA[c] * pr[p * 16 + e] + coefB[c];
        }
        xt[sub][48 + f * 16 + e] = acc;
    }
    __syncthreads();

    // h1 = relu(x @ W1 + b1): lane e computes j = e + 16*r, r=0..3
    float h1[4];
    #pragma unroll
    for (int r = 0; r < 4; ++r) h1[r] = sb1[e + 16 * r];
    for (int k = 0; k < 112; ++k) {
        float xk = xt[sub][k];
        #pragma unroll
        for (int r = 0; r < 4; ++r) h1[r] += xk * sW1[k * 64 + e + 16 * r];
    }
    #pragma unroll
    for (int r = 0; r < 4; ++r) h1t[sub][e + 16 * r] = fmaxf(h1[r], 0.f);
    __syncthreads();

    // h2 = relu(h1 @ W2 + b2): lane e computes j = e, e+16
    float h2[2];
    #pragma unroll
    for (int r = 0; r < 2; ++r) h2[r] = sb2[e + 16 * r];
    for (int k = 0; k < 64; ++k) {
        float hk = h1t[sub][k];
        #pragma unroll
        for (int r = 0; r < 2; ++r) h2[r] += hk * sW2[k * 32 + e + 16 * r];
    }
    float part = fmaxf(h2[0], 0.f) * sW3[e] + fmaxf(h2[1], 0.f) * sW3[16 + e];
    part += __shfl_xor(part, 1);
    part += __shfl_xor(part, 2);
    part += __shfl_xor(part, 4);
    part += __shfl_xor(part, 8);
    if (e == 0) {
        float t = part + b3[0];
        out[b] = 1.f / (1.f + expf(-t));
    }
}

extern "C" void kernel_launch(void* const* d_in, const int* in_sizes, int n_in,
                              void* d_out, int out_size, void* d_ws, size_t ws_size,
                              hipStream_t stream) {
    const int* uid     = (const int*)d_in[0];
    const int* mid     = (const int*)d_in[1];
    const int* yr      = (const int*)d_in[2];
    const int* ids_ug  = (const int*)d_in[3];
    const int* ids_urb = (const int*)d_in[4];
    const int* ids_mg  = (const int*)d_in[5];
    const int* ids_mt  = (const int*)d_in[6];
    const int* len_ug  = (const int*)d_in[7];
    const int* len_urb = (const int*)d_in[8];
    const int* len_mg  = (const int*)d_in[9];
    const int* len_mt  = (const int*)d_in[10];
    const float* emb_user  = (const float*)d_in[11];
    const float* emb_movie = (const float*)d_in[12];
    const float* emb_tag   = (const float*)d_in[13];
    const float* emb_genre = (const float*)d_in[14];
    const float* emb_year  = (const float*)d_in[15];
    const float* att_movie = (const float*)d_in[16];
    const float* att_tag   = (const float*)d_in[17];
    const float* att_genre = (const float*)d_in[18];
    const float* bn_gamma  = (const float*)d_in[19];
    const float* bn_beta   = (const float*)d_in[20];
    const float* alpha     = (const float*)d_in[21];
    const float* W1 = (const float*)d_in[22];
    const float* b1 = (const float*)d_in[23];
    const float* W2 = (const float*)d_in[24];
    const float* b2 = (const float*)d_in[25];
    const float* W3 = (const float*)d_in[26];
    const float* b3 = (const float*)d_in[27];
    float* out = (float*)d_out;

    float*  pooled = (float*)d_ws;
    double* sums   = (double*)((char*)d_ws + POOLED_BYTES);
    double* sumsqs = sums + NCH;
    float*  coefA  = (float*)(sums + 2 * NCH);
    float*  coefB  = coefA + NCH;

    zero_stats_kernel<<<1, 256, 0, stream>>>(sums);
    pool_kernel<<<dim3(BATCH / SPB, 4), 256, 0, stream>>>(
        ids_ug, ids_urb, ids_mg, ids_mt,
        len_ug, len_urb, len_mg, len_mt,
        emb_movie, emb_tag, emb_genre,
        att_movie, att_tag, att_genre,
        pooled, sums, sumsqs);
    coef_kernel<<<1, 384, 0, stream>>>(sums, sumsqs, bn_gamma, bn_beta, alpha,
                                       coefA, coefB);
    final_kernel<<<BATCH / SPB, 256, 0, stream>>>(
        uid, mid, yr, emb_user, emb_movie, emb_year,
        pooled, coefA, coefB, W1, b1, W2, b2, W3, b3, out);
}

// Round 2
// 210.517 us; speedup vs baseline: 1.0139x; 1.0139x over previous
//
#include <hip/hip_runtime.h>
#include <math.h>

#define BATCH 8192
#define L 100
#define EMB 16
#define NCH 384  // 4 fields * 6 pools * 16 emb channels

// ---------------- workspace layout ----------------
// pooled : float [4][BATCH][6][16]  = 12,582,912 B
// sums   : double[384]; sumsqs : double[384]
// coefA  : float [384]; coefB  : float [384]
#define POOLED_FLOATS (4 * BATCH * 96)
#define POOLED_BYTES  (POOLED_FLOATS * 4)

// pool: 4 lanes per sample, float4 gathers, loop truncated at ln.
// Padded tail (l >= ln): v = 0 contributes nothing to s/ssq/att; l2 = 0 never
// beats bestmx (strict >, first valid iter sets bestmx >= 0) and maps to 9999
// which never beats bestmn (first valid iter sets bestmn <= 9999 via strict <);
// softmax denominator gets exp(0) * (L - ln) added analytically.
__global__ __launch_bounds__(256) void pool_kernel(
    const int* __restrict__ ids_ug, const int* __restrict__ ids_urb,
    const int* __restrict__ ids_mg, const int* __restrict__ ids_mt,
    const int* __restrict__ len_ug, const int* __restrict__ len_urb,
    const int* __restrict__ len_mg, const int* __restrict__ len_mt,
    const float* __restrict__ emb_movie, const float* __restrict__ emb_tag,
    const float* __restrict__ emb_genre,
    const float* __restrict__ att_movie, const float* __restrict__ att_tag,
    const float* __restrict__ att_genre,
    float* __restrict__ pooled, double* __restrict__ sums, double* __restrict__ sumsqs)
{
    const int f = blockIdx.y;
    const int* ids; const int* lens; const float* tab; const float* atab;
    switch (f) {
        case 0: ids = ids_ug;  lens = len_ug;  tab = emb_genre; atab = att_genre; break;
        case 1: ids = ids_urb; lens = len_urb; tab = emb_movie; atab = att_movie; break;
        case 2: ids = ids_mg;  lens = len_mg;  tab = emb_genre; atab = att_genre; break;
        default:ids = ids_mt;  lens = len_mt;  tab = emb_tag;   atab = att_tag;   break;
    }
    const int tid = threadIdx.x;
    const int sub = tid >> 2;       // sample within block (0..63)
    const int c   = tid & 3;        // float4 chunk (dims 4c..4c+3)
    const int b   = blockIdx.x * 64 + sub;
    const int ln  = lens[b];

    const int* idrow = ids + (size_t)b * L;
    const float4* __restrict__ tab4 = (const float4*)tab;

    float4 s   = make_float4(0.f, 0.f, 0.f, 0.f);
    float4 ssq = s, att = s, mxv = s, mnv = s;
    float expsum = (float)(L - ln);   // analytic padded-tail contribution
    float bestmx = -1e30f, bestmn = 1e30f;

    for (int l = 0; l < ln; ++l) {
        const int id = idrow[l];
        const float4 v = tab4[(size_t)id * 4 + c];
        const float aw = atab[id];
        float4 v2;
        v2.x = v.x * v.x; v2.y = v.y * v.y; v2.z = v.z * v.z; v2.w = v.w * v.w;
        s.x += v.x; s.y += v.y; s.z += v.z; s.w += v.w;
        ssq.x += v2.x; ssq.y += v2.y; ssq.z += v2.z; ssq.w += v2.w;
        float pl2 = (v2.x + v2.y) + (v2.z + v2.w);
        float l2 = pl2 + __shfl_xor(pl2, 1);
        l2 += __shfl_xor(l2, 2);
        if (l2 > bestmx) { bestmx = l2; mxv = v; }   // first-max (strict >)
        float l2m = (l2 == 0.0f) ? 9999.0f : l2;
        if (l2m < bestmn) { bestmn = l2m; mnv = v; } // first-min (strict <)
        float ew = __expf(aw);
        expsum += ew;
        att.x += v.x * ew; att.y += v.y * ew; att.z += v.z * ew; att.w += v.w * ew;
    }

    float4 mean;
    mean.x = s.x * (1.0f / L); mean.y = s.y * (1.0f / L);
    mean.z = s.z * (1.0f / L); mean.w = s.w * (1.0f / L);
    float4 ko;
    ko.x = 0.5f * (s.x * s.x - ssq.x); ko.y = 0.5f * (s.y * s.y - ssq.y);
    ko.z = 0.5f * (s.z * s.z - ssq.z); ko.w = 0.5f * (s.w * s.w - ssq.w);
    float pk = (ko.x * ko.x + ko.y * ko.y) + (ko.z * ko.z + ko.w * ko.w);
    float kn2 = pk + __shfl_xor(pk, 1);
    kn2 += __shfl_xor(kn2, 2);
    float rn = 1.0f / fmaxf(sqrtf(kn2), 1e-12f);
    ko.x *= rn; ko.y *= rn; ko.z *= rn; ko.w *= rn;
    float ie = 1.0f / expsum;
    att.x *= ie; att.y *= ie; att.z *= ie; att.w *= ie;

    float4 pv[6] = { s, mean, mxv, mnv, ko, att };

    __shared__ float tile[64][96];
    float4* prow = (float4*)(pooled + ((size_t)(f * BATCH + b)) * 96);
    #pragma unroll
    for (int p = 0; p < 6; ++p) {
        prow[p * 4 + c] = pv[p];
        *(float4*)&tile[sub][p * 16 + c * 4] = pv[p];
    }
    __syncthreads();
    // block-level partial stats -> double atomics (96 channels for this field)
    if (tid < 96) {
        float sm = 0.f, sq = 0.f;
        #pragma unroll 8
        for (int s2 = 0; s2 < 64; ++s2) {
            float x = tile[s2][tid];
            sm += x;
            sq += x * x;
        }
        atomicAdd(&sums[f * 96 + tid],   (double)sm);
        atomicAdd(&sumsqs[f * 96 + tid], (double)sq);
    }
}

__global__ __launch_bounds__(384) void coef_kernel(
    const double* __restrict__ sums, const double* __restrict__ sumsqs,
    const float* __restrict__ gamma, const float* __restrict__ beta,
    const float* __restrict__ alpha,
    float* __restrict__ coefA, float* __restrict__ coefB)
{
    int c = threadIdx.x;          // 0..383  = f*96 + p*16 + e
    if (c >= NCH) return;
    int f = c / 96;
    int p = (c % 96) >> 4;
    double mu  = sums[c]   * (1.0 / BATCH);
    double var = sumsqs[c] * (1.0 / BATCH) - mu * mu;
    float inv = (float)(1.0 / sqrt(var + 1e-5));
    float g  = gamma[c];
    float bb = beta[c];
    float amax = -1e30f;
    for (int q = 0; q < 6; ++q) amax = fmaxf(amax, alpha[f * 6 + q]);
    float wsum = 0.f;
    for (int q = 0; q < 6; ++q) wsum += __expf(alpha[f * 6 + q] - amax);
    float wp = __expf(alpha[f * 6 + p] - amax) / wsum;
    float muf = (float)mu;
    coefA[c] = wp * g * inv;
    coefB[c] = wp * (bb - g * muf * inv);
}

#define SPB 16
__global__ __launch_bounds__(256) void final_kernel(
    const int* __restrict__ uid, const int* __restrict__ mid, const int* __restrict__ yr,
    const float* __restrict__ emb_user, const float* __restrict__ emb_movie,
    const float* __restrict__ emb_year,
    const float* __restrict__ pooled,
    const float* __restrict__ coefA, const float* __restrict__ coefB,
    const float* __restrict__ W1, const float* __restrict__ b1,
    const float* __restrict__ W2, const float* __restrict__ b2,
    const float* __restrict__ W3, const float* __restrict__ b3,
    float* __restrict__ out)
{
    __shared__ float sW1[112 * 64];
    __shared__ float sW2[64 * 32];
    __shared__ float sW3[32];
    __shared__ float sb1[64];
    __shared__ float sb2[32];
    __shared__ float xt[SPB][112];
    __shared__ float h1t[SPB][64];

    const int tid = threadIdx.x;
    for (int i = tid; i < 112 * 64; i += 256) sW1[i] = W1[i];
    for (int i = tid; i < 64 * 32;  i += 256) sW2[i] = W2[i];
    if (tid < 32) sW3[tid] = W3[tid];
    if (tid < 64) sb1[tid] = b1[tid];
    if (tid < 32) sb2[tid] = b2[tid];

    const int sub = tid >> 4;
    const int e   = tid & 15;
    const int b   = blockIdx.x * SPB + sub;

    xt[sub][e]      = emb_user [(size_t)uid[b] * EMB + e];
    xt[sub][16 + e] = emb_movie[(size_t)mid[b] * EMB + e];
    xt[sub][32 + e] = emb_year [(size_t)yr[b]  * EMB + e];

    #pragma unroll
    for (int f = 0; f < 4; ++f) {
        const float* pr = pooled + ((size_t)(f * BATCH + b)) * 96;
        float acc = 0.f;
        #pragma unroll
        for (int p = 0; p < 6; ++p) {
            int c = f * 96 + p * 16 + e;
            acc += coefA[c] * pr[p * 16 + e] + coefB[c];
        }
        xt[sub][48 + f * 16 + e] = acc;
    }
    __syncthreads();

    float h1[4];
    #pragma unroll
    for (int r = 0; r < 4; ++r) h1[r] = sb1[e + 16 * r];
    for (int k = 0; k < 112; ++k) {
        float xk = xt[sub][k];
        #pragma unroll
        for (int r = 0; r < 4; ++r) h1[r] += xk * sW1[k * 64 + e + 16 * r];
    }
    #pragma unroll
    for (int r = 0; r < 4; ++r) h1t[sub][e + 16 * r] = fmaxf(h1[r], 0.f);
    __syncthreads();

    float h2[2];
    #pragma unroll
    for (int r = 0; r < 2; ++r) h2[r] = sb2[e + 16 * r];
    for (int k = 0; k < 64; ++k) {
        float hk = h1t[sub][k];
        #pragma unroll
        for (int r = 0; r < 2; ++r) h2[r] += hk * sW2[k * 32 + e + 16 * r];
    }
    float part = fmaxf(h2[0], 0.f) * sW3[e] + fmaxf(h2[1], 0.f) * sW3[16 + e];
    part += __shfl_xor(part, 1);
    part += __shfl_xor(part, 2);
    part += __shfl_xor(part, 4);
    part += __shfl_xor(part, 8);
    if (e == 0) {
        float t = part + b3[0];
        out[b] = 1.f / (1.f + __expf(-t));
    }
}

extern "C" void kernel_launch(void* const* d_in, const int* in_sizes, int n_in,
                              void* d_out, int out_size, void* d_ws, size_t ws_size,
                              hipStream_t stream) {
    const int* uid     = (const int*)d_in[0];
    const int* mid     = (const int*)d_in[1];
    const int* yr      = (const int*)d_in[2];
    const int* ids_ug  = (const int*)d_in[3];
    const int* ids_urb = (const int*)d_in[4];
    const int* ids_mg  = (const int*)d_in[5];
    const int* ids_mt  = (const int*)d_in[6];
    const int* len_ug  = (const int*)d_in[7];
    const int* len_urb = (const int*)d_in[8];
    const int* len_mg  = (const int*)d_in[9];
    const int* len_mt  = (const int*)d_in[10];
    const float* emb_user  = (const float*)d_in[11];
    const float* emb_movie = (const float*)d_in[12];
    const float* emb_tag   = (const float*)d_in[13];
    const float* emb_genre = (const float*)d_in[14];
    const float* emb_year  = (const float*)d_in[15];
    const float* att_movie = (const float*)d_in[16];
    const float* att_tag   = (const float*)d_in[17];
    const float* att_genre = (const float*)d_in[18];
    const float* bn_gamma  = (const float*)d_in[19];
    const float* bn_beta   = (const float*)d_in[20];
    const float* alpha     = (const float*)d_in[21];
    const float* W1 = (const float*)d_in[22];
    const float* b1 = (const float*)d_in[23];
    const float* W2 = (const float*)d_in[24];
    const float* b2 = (const float*)d_in[25];
    const float* W3 = (const float*)d_in[26];
    const float* b3 = (const float*)d_in[27];
    float* out = (float*)d_out;

    float*  pooled = (float*)d_ws;
    double* sums   = (double*)((char*)d_ws + POOLED_BYTES);
    double* sumsqs = sums + NCH;
    float*  coefA  = (float*)(sums + 2 * NCH);
    float*  coefB  = coefA + NCH;

    hipMemsetAsync(sums, 0, 2 * NCH * sizeof(double), stream);
    pool_kernel<<<dim3(BATCH / 64, 4), 256, 0, stream>>>(
        ids_ug, ids_urb, ids_mg, ids_mt,
        len_ug, len_urb, len_mg, len_mt,
        emb_movie, emb_tag, emb_genre,
        att_movie, att_tag, att_genre,
        pooled, sums, sumsqs);
    coef_kernel<<<1, 384, 0, stream>>>(sums, sumsqs, bn_gamma, bn_beta, alpha,
                                       coefA, coefB);
    final_kernel<<<BATCH / SPB, 256, 0, stream>>>(
        uid, mid, yr, emb_user, emb_movie, emb_year,
        pooled, coefA, coefB, W1, b1, W2, b2, W3, b3, out);
}

// Round 3
// 172.537 us; speedup vs baseline: 1.2371x; 1.2201x over previous
//
#include <hip/hip_runtime.h>
#include <math.h>

#define BATCH 8192
#define L 100
#define EMB 16
#define NCH 384  // 4 fields * 6 pools * 16 emb channels

// ---------------- workspace layout ----------------
// pooled : float [4][BATCH][6][16]  = 12,582,912 B
// sums   : double[384]; sumsqs : double[384]
// coefA  : float [384]; coefB  : float [384]
#define POOLED_FLOATS (4 * BATCH * 96)
#define POOLED_BYTES  (POOLED_FLOATS * 4)

// pool: 16 lanes/sample = 4 phases (l-split) x 4 chunks (float4 of EMB).
// Phase j processes l = j, j+4, ... < ln (truncated; padded tail handled
// analytically). First-index argmax/argmin preserved by carrying l and
// merging phases with tie -> smaller l.
__global__ __launch_bounds__(256) void pool_kernel(
    const int* __restrict__ ids_ug, const int* __restrict__ ids_urb,
    const int* __restrict__ ids_mg, const int* __restrict__ ids_mt,
    const int* __restrict__ len_ug, const int* __restrict__ len_urb,
    const int* __restrict__ len_mg, const int* __restrict__ len_mt,
    const float* __restrict__ emb_movie, const float* __restrict__ emb_tag,
    const float* __restrict__ emb_genre,
    const float* __restrict__ att_movie, const float* __restrict__ att_tag,
    const float* __restrict__ att_genre,
    float* __restrict__ pooled, double* __restrict__ sums, double* __restrict__ sumsqs)
{
    const int f = blockIdx.y;
    const int* ids; const int* lens; const float* tab; const float* atab;
    switch (f) {
        case 0: ids = ids_ug;  lens = len_ug;  tab = emb_genre; atab = att_genre; break;
        case 1: ids = ids_urb; lens = len_urb; tab = emb_movie; atab = att_movie; break;
        case 2: ids = ids_mg;  lens = len_mg;  tab = emb_genre; atab = att_genre; break;
        default:ids = ids_mt;  lens = len_mt;  tab = emb_tag;   atab = att_tag;   break;
    }
    const int tid = threadIdx.x;
    const int sub = tid >> 4;        // sample within block (0..15)
    const int j   = (tid >> 2) & 3;  // l-phase
    const int c   = tid & 3;         // float4 chunk (dims 4c..4c+3)
    const int b   = blockIdx.x * 16 + sub;
    const int ln  = lens[b];

    const int* idrow = ids + (size_t)b * L;
    const float4* __restrict__ tab4 = (const float4*)tab;

    float4 s   = make_float4(0.f, 0.f, 0.f, 0.f);
    float4 ssq = s, att = s, mxv = s, mnv = s;
    float expsum = 0.f;
    float bestmx = -1e30f; int lx = 0x7fffffff;
    float bestmn =  1e30f; int lm = 0x7fffffff;

    int l  = j;
    int id = (l < ln) ? idrow[l] : 0;
    while (l < ln) {
        const int nl  = l + 4;
        const int nid = (nl < ln) ? idrow[nl] : 0;   // prefetch next id
        const float4 v = tab4[(size_t)id * 4 + c];
        const float aw = atab[id];
        float4 v2;
        v2.x = v.x * v.x; v2.y = v.y * v.y; v2.z = v.z * v.z; v2.w = v.w * v.w;
        s.x += v.x; s.y += v.y; s.z += v.z; s.w += v.w;
        ssq.x += v2.x; ssq.y += v2.y; ssq.z += v2.z; ssq.w += v2.w;
        float pl2 = (v2.x + v2.y) + (v2.z + v2.w);
        float l2 = pl2 + __shfl_xor(pl2, 1);   // reduce over chunk quad
        l2 += __shfl_xor(l2, 2);
        if (l2 > bestmx) { bestmx = l2; lx = l; mxv = v; }     // first-max
        float l2m = (l2 == 0.0f) ? 9999.0f : l2;
        if (l2m < bestmn) { bestmn = l2m; lm = l; mnv = v; }   // first-min
        float ew = __expf(aw);
        expsum += ew;
        att.x += v.x * ew; att.y += v.y * ew; att.z += v.z * ew; att.w += v.w * ew;
        l = nl; id = nid;
    }

    // cross-phase merges (xor 4, then 8; chunk index c preserved)
    #pragma unroll
    for (int m = 4; m <= 8; m <<= 1) {
        // argmax merge
        float obx = __shfl_xor(bestmx, m);
        int   olx = __shfl_xor(lx, m);
        float ax = __shfl_xor(mxv.x, m), ay = __shfl_xor(mxv.y, m);
        float az = __shfl_xor(mxv.z, m), aw2 = __shfl_xor(mxv.w, m);
        if (obx > bestmx || (obx == bestmx && olx < lx)) {
            bestmx = obx; lx = olx; mxv = make_float4(ax, ay, az, aw2);
        }
        // argmin merge
        float obn = __shfl_xor(bestmn, m);
        int   olm = __shfl_xor(lm, m);
        float bx = __shfl_xor(mnv.x, m), by = __shfl_xor(mnv.y, m);
        float bz = __shfl_xor(mnv.z, m), bw = __shfl_xor(mnv.w, m);
        if (obn < bestmn || (obn == bestmn && olm < lm)) {
            bestmn = obn; lm = olm; mnv = make_float4(bx, by, bz, bw);
        }
        // sums
        s.x += __shfl_xor(s.x, m); s.y += __shfl_xor(s.y, m);
        s.z += __shfl_xor(s.z, m); s.w += __shfl_xor(s.w, m);
        ssq.x += __shfl_xor(ssq.x, m); ssq.y += __shfl_xor(ssq.y, m);
        ssq.z += __shfl_xor(ssq.z, m); ssq.w += __shfl_xor(ssq.w, m);
        att.x += __shfl_xor(att.x, m); att.y += __shfl_xor(att.y, m);
        att.z += __shfl_xor(att.z, m); att.w += __shfl_xor(att.w, m);
        expsum += __shfl_xor(expsum, m);
    }
    expsum += (float)(L - ln);   // analytic padded-tail exp(0) contributions

    float4 mean;
    mean.x = s.x * (1.0f / L); mean.y = s.y * (1.0f / L);
    mean.z = s.z * (1.0f / L); mean.w = s.w * (1.0f / L);
    float4 ko;
    ko.x = 0.5f * (s.x * s.x - ssq.x); ko.y = 0.5f * (s.y * s.y - ssq.y);
    ko.z = 0.5f * (s.z * s.z - ssq.z); ko.w = 0.5f * (s.w * s.w - ssq.w);
    float pk = (ko.x * ko.x + ko.y * ko.y) + (ko.z * ko.z + ko.w * ko.w);
    float kn2 = pk + __shfl_xor(pk, 1);
    kn2 += __shfl_xor(kn2, 2);
    float rn = 1.0f / fmaxf(sqrtf(kn2), 1e-12f);
    ko.x *= rn; ko.y *= rn; ko.z *= rn; ko.w *= rn;
    float ie = 1.0f / expsum;
    att.x *= ie; att.y *= ie; att.z *= ie; att.w *= ie;

    float4 pv[6] = { s, mean, mxv, mnv, ko, att };

    __shared__ float tile[16][100];   // +4 pad: row stride not multiple of 32
    float4* prow = (float4*)(pooled + ((size_t)(f * BATCH + b)) * 96);
    if (j == 0) {
        #pragma unroll
        for (int p = 0; p < 6; ++p) {
            prow[p * 4 + c] = pv[p];
            *(float4*)&tile[sub][p * 16 + c * 4] = pv[p];
        }
    }
    __syncthreads();
    // block-level partial stats -> double atomics (96 channels for this field)
    if (tid < 96) {
        float sm = 0.f, sq = 0.f;
        #pragma unroll
        for (int s2 = 0; s2 < 16; ++s2) {
            float x = tile[s2][tid];
            sm += x;
            sq += x * x;
        }
        atomicAdd(&sums[f * 96 + tid],   (double)sm);
        atomicAdd(&sumsqs[f * 96 + tid], (double)sq);
    }
}

__global__ __launch_bounds__(384) void coef_kernel(
    const double* __restrict__ sums, const double* __restrict__ sumsqs,
    const float* __restrict__ gamma, const float* __restrict__ beta,
    const float* __restrict__ alpha,
    float* __restrict__ coefA, float* __restrict__ coefB)
{
    int c = threadIdx.x;          // 0..383  = f*96 + p*16 + e
    if (c >= NCH) return;
    int f = c / 96;
    int p = (c % 96) >> 4;
    double mu  = sums[c]   * (1.0 / BATCH);
    double var = sumsqs[c] * (1.0 / BATCH) - mu * mu;
    float inv = (float)(1.0 / sqrt(var + 1e-5));
    float g  = gamma[c];
    float bb = beta[c];
    float amax = -1e30f;
    for (int q = 0; q < 6; ++q) amax = fmaxf(amax, alpha[f * 6 + q]);
    float wsum = 0.f;
    for (int q = 0; q < 6; ++q) wsum += __expf(alpha[f * 6 + q] - amax);
    float wp = __expf(alpha[f * 6 + p] - amax) / wsum;
    float muf = (float)mu;
    coefA[c] = wp * g * inv;
    coefB[c] = wp * (bb - g * muf * inv);
}

#define SPB 16
__global__ __launch_bounds__(256) void final_kernel(
    const int* __restrict__ uid, const int* __restrict__ mid, const int* __restrict__ yr,
    const float* __restrict__ emb_user, const float* __restrict__ emb_movie,
    const float* __restrict__ emb_year,
    const float* __restrict__ pooled,
    const float* __restrict__ coefA, const float* __restrict__ coefB,
    const float* __restrict__ W1, const float* __restrict__ b1,
    const float* __restrict__ W2, const float* __restrict__ b2,
    const float* __restrict__ W3, const float* __restrict__ b3,
    float* __restrict__ out)
{
    __shared__ float sW1[112 * 64];   // [k][j], j contiguous
    __shared__ float sW2[64 * 32];
    __shared__ float sW3[32];
    __shared__ float sb1[64];
    __shared__ float sb2[32];
    __shared__ float xt[SPB][112];
    __shared__ float h1t[SPB][64];

    const int tid = threadIdx.x;
    for (int i = tid; i < 112 * 16; i += 256)
        ((float4*)sW1)[i] = ((const float4*)W1)[i];
    for (int i = tid; i < 64 * 8; i += 256)
        ((float4*)sW2)[i] = ((const float4*)W2)[i];
    if (tid < 32) sW3[tid] = W3[tid];
    if (tid < 64) sb1[tid] = b1[tid];
    if (tid < 32) sb2[tid] = b2[tid];

    const int sub = tid >> 4;
    const int e   = tid & 15;
    const int b   = blockIdx.x * SPB + sub;

    xt[sub][e]      = emb_user [(size_t)uid[b] * EMB + e];
    xt[sub][16 + e] = emb_movie[(size_t)mid[b] * EMB + e];
    xt[sub][32 + e] = emb_year [(size_t)yr[b]  * EMB + e];

    #pragma unroll
    for (int f = 0; f < 4; ++f) {
        const float* pr = pooled + ((size_t)(f * BATCH + b)) * 96;
        float acc = 0.f;
        #pragma unroll
        for (int p = 0; p < 6; ++p) {
            int c = f * 96 + p * 16 + e;
            acc += coefA[c] * pr[p * 16 + e] + coefB[c];
        }
        xt[sub][48 + f * 16 + e] = acc;
    }
    __syncthreads();

    // h1 = relu(x @ W1 + b1): lane e computes j = 4e..4e+3 via float4
    float4 h1 = ((float4*)sb1)[e];
    for (int k = 0; k < 112; ++k) {
        float xk = xt[sub][k];
        float4 w = ((float4*)sW1)[k * 16 + e];
        h1.x += xk * w.x; h1.y += xk * w.y; h1.z += xk * w.z; h1.w += xk * w.w;
    }
    float4 h1r;
    h1r.x = fmaxf(h1.x, 0.f); h1r.y = fmaxf(h1.y, 0.f);
    h1r.z = fmaxf(h1.z, 0.f); h1r.w = fmaxf(h1.w, 0.f);
    *(float4*)&h1t[sub][e * 4] = h1r;
    __syncthreads();

    // h2 = relu(h1 @ W2 + b2): lane e computes j = 2e, 2e+1 via float2
    float2 h2 = ((float2*)sb2)[e];
    for (int k = 0; k < 64; ++k) {
        float hk = h1t[sub][k];
        float2 w = ((float2*)sW2)[k * 16 + e];
        h2.x += hk * w.x; h2.y += hk * w.y;
    }
    float part = fmaxf(h2.x, 0.f) * sW3[2 * e] + fmaxf(h2.y, 0.f) * sW3[2 * e + 1];
    part += __shfl_xor(part, 1);
    part += __shfl_xor(part, 2);
    part += __shfl_xor(part, 4);
    part += __shfl_xor(part, 8);
    if (e == 0) {
        float t = part + b3[0];
        out[b] = 1.f / (1.f + __expf(-t));
    }
}

extern "C" void kernel_launch(void* const* d_in, const int* in_sizes, int n_in,
                              void* d_out, int out_size, void* d_ws, size_t ws_size,
                              hipStream_t stream) {
    const int* uid     = (const int*)d_in[0];
    const int* mid     = (const int*)d_in[1];
    const int* yr      = (const int*)d_in[2];
    const int* ids_ug  = (const int*)d_in[3];
    const int* ids_urb = (const int*)d_in[4];
    const int* ids_mg  = (const int*)d_in[5];
    const int* ids_mt  = (const int*)d_in[6];
    const int* len_ug  = (const int*)d_in[7];
    const int* len_urb = (const int*)d_in[8];
    const int* len_mg  = (const int*)d_in[9];
    const int* len_mt  = (const int*)d_in[10];
    const float* emb_user  = (const float*)d_in[11];
    const float* emb_movie = (const float*)d_in[12];
    const float* emb_tag   = (const float*)d_in[13];
    const float* emb_genre = (const float*)d_in[14];
    const float* emb_year  = (const float*)d_in[15];
    const float* att_movie = (const float*)d_in[16];
    const float* att_tag   = (const float*)d_in[17];
    const float* att_genre = (const float*)d_in[18];
    const float* bn_gamma  = (const float*)d_in[19];
    const float* bn_beta   = (const float*)d_in[20];
    const float* alpha     = (const float*)d_in[21];
    const float* W1 = (const float*)d_in[22];
    const float* b1 = (const float*)d_in[23];
    const float* W2 = (const float*)d_in[24];
    const float* b2 = (const float*)d_in[25];
    const float* W3 = (const float*)d_in[26];
    const float* b3 = (const float*)d_in[27];
    float* out = (float*)d_out;

    float*  pooled = (float*)d_ws;
    double* sums   = (double*)((char*)d_ws + POOLED_BYTES);
    double* sumsqs = sums + NCH;
    float*  coefA  = (float*)(sums + 2 * NCH);
    float*  coefB  = coefA + NCH;

    hipMemsetAsync(sums, 0, 2 * NCH * sizeof(double), stream);
    pool_kernel<<<dim3(BATCH / 16, 4), 256, 0, stream>>>(
        ids_ug, ids_urb, ids_mg, ids_mt,
        len_ug, len_urb, len_mg, len_mt,
        emb_movie, emb_tag, emb_genre,
        att_movie, att_tag, att_genre,
        pooled, sums, sumsqs);
    coef_kernel<<<1, 384, 0, stream>>>(sums, sumsqs, bn_gamma, bn_beta, alpha,
                                       coefA, coefB);
    final_kernel<<<BATCH / SPB, 256, 0, stream>>>(
        uid, mid, yr, emb_user, emb_movie, emb_year,
        pooled, coefA, coefB, W1, b1, W2, b2, W3, b3, out);
}